// Round 9
// baseline (458.787 us; speedup 1.0000x reference)
//
#include <hip/hip_runtime.h>

#define DIM 64
#define K_CODES 512
#define N_VEC 131072
#define NREP 16
#define Q_OFF 1
#define PERP_OFF 8388609
#define ENC_OFF 8388610

using bfrag = __attribute__((ext_vector_type(8))) short;  // 8 bf16 = 4 VGPR
using ffrag = __attribute__((ext_vector_type(4))) float;  // 4 f32 acc

// Exact 3-way bf16 truncation split: x == x0 + x1 + x2 (and the
// reconstruction (x0+x1)+x2 is bit-exact: each partial sum spans <=24 bits).
__device__ __forceinline__ void split3(float x, short& h0, short& h1, short& h2)
{
    unsigned u0 = __float_as_uint(x);
    h0 = (short)(u0 >> 16);
    float r = x - __uint_as_float(u0 & 0xFFFF0000u);     // exact
    unsigned u1 = __float_as_uint(r);
    h1 = (short)(u1 >> 16);
    float r2 = r - __uint_as_float(u1 & 0xFFFF0000u);    // exact
    h2 = (short)(__float_as_uint(r2) >> 16);             // r2 fits bf16 exactly
}

__device__ __forceinline__ float b2f(short h)
{
    return __uint_as_float(((unsigned)(unsigned short)h) << 16);
}

// ---------------------------------------------------------------------------
// ||e||^2 per code (512 values, one block).
// ---------------------------------------------------------------------------
__global__ __launch_bounds__(512) void ee_kernel(const float* __restrict__ emb_w,
                                                 float* __restrict__ ee)
{
    const int k = threadIdx.x;
    const float4* e4 = reinterpret_cast<const float4*>(emb_w + (size_t)k * DIM);
    float s0 = 0, s1 = 0, s2 = 0, s3 = 0;
#pragma unroll
    for (int d4 = 0; d4 < 16; ++d4) {
        const float4 v = e4[d4];
        s0 = fmaf(v.x, v.x, s0); s1 = fmaf(v.y, v.y, s1);
        s2 = fmaf(v.z, v.z, s2); s3 = fmaf(v.w, v.w, s3);
    }
    ee[k] = (s0 + s1) + (s2 + s3);
}

// ---------------------------------------------------------------------------
// pre-split + pre-pack codebook into per-lane MFMA B-fragments (192 KB).
// epack[((ct*2+db)*3+s)*64+lane]: code c = ct*16+(lane&15),
// d = db*32+(lane>>4)*8+0..7, split s.
// ---------------------------------------------------------------------------
__global__ __launch_bounds__(256) void epack_kernel(const float* __restrict__ emb_w,
                                                    bfrag* __restrict__ epack)
{
    const int t = blockIdx.x * 256 + threadIdx.x;   // 0..4095
    const int lane = t & 63;
    const int db = (t >> 6) & 1;
    const int ct = t >> 7;                          // 0..31
    const int c  = ct * 16 + (lane & 15);
    const int d0 = db * 32 + (lane >> 4) * 8;
    const float* src = emb_w + (size_t)c * DIM + d0;
    bfrag f0, f1, f2;
#pragma unroll
    for (int j = 0; j < 8; ++j) {
        short a, b, cc;
        split3(src[j], a, b, cc);
        f0[j] = a; f1[j] = b; f2[j] = cc;
    }
    const int base = (ct * 2 + db) * 3;
    epack[(base + 0) * 64 + lane] = f0;
    epack[(base + 1) * 64 + lane] = f1;
    epack[(base + 2) * 64 + lane] = f2;
}

// ---------------------------------------------------------------------------
// argmin via 6-pass split-bf16 MFMA. Wave owns 16 vectors; block = 4 waves
// = 64 vectors; grid 2048. Live set ~100 VGPR (no spill at (256,2)).
// Fused outputs, all from registers/LDS-index only:
//   - FULL one-hot rows (zeros+one computed per element; no zero kernel,
//     no read-modify-write) as 4x512B wave-stores per row
//   - idx
//   - counts into 16 replicas
//   - dw into 16 replicas, x reconstructed exactly from its bf16 splits
// Tie rule: ascending-k scan + strict <, cross-lane prefers smaller k
// == numpy argmin (first minimum).
// ---------------------------------------------------------------------------
__global__ __launch_bounds__(256, 2) void argmin_mfma_kernel(
    const float* __restrict__ inputs,
    const bfrag* __restrict__ epack,
    const float* __restrict__ eeg,
    int* __restrict__ idx,
    float* __restrict__ counts_rep,
    float* __restrict__ dwrep,
    float* __restrict__ enc)
{
    __shared__ int sBK[64];

    const int t = threadIdx.x;
    const int wv = t >> 6;
    const int lane = t & 63;
    const int r16 = lane & 15;
    const int quad = lane >> 4;
    const size_t v0 = (size_t)blockIdx.x * 64 + wv * 16;
    const int rep = blockIdx.x & (NREP - 1);

    // ---- load + exact-split X into A-fragments (24 VGPRs) ----
    bfrag xf[2][3];
#pragma unroll
    for (int db = 0; db < 2; ++db) {
        const float* src = inputs + (v0 + r16) * DIM + db * 32 + quad * 8;
        const float4 va = *reinterpret_cast<const float4*>(src);
        const float4 vb = *reinterpret_cast<const float4*>(src + 4);
        float vals[8] = {va.x, va.y, va.z, va.w, vb.x, vb.y, vb.z, vb.w};
        bfrag f0, f1, f2;
#pragma unroll
        for (int j = 0; j < 8; ++j) {
            short a, b, c;
            split3(vals[j], a, b, c);
            f0[j] = a; f1[j] = b; f2[j] = c;
        }
        xf[db][0] = f0; xf[db][1] = f1; xf[db][2] = f2;
    }

    float best[4] = {3.4e38f, 3.4e38f, 3.4e38f, 3.4e38f};
    int bestk[4] = {0, 0, 0, 0};

    constexpr int PI[6] = {0, 0, 1, 0, 2, 1};
    constexpr int PJ[6] = {0, 1, 0, 2, 0, 1};

    // ---- prefetch ct=0 B-fragments ----
    bfrag eC[2][3];
    float eelC;
#pragma unroll
    for (int db = 0; db < 2; ++db)
#pragma unroll
        for (int s = 0; s < 3; ++s)
            eC[db][s] = epack[(db * 3 + s) * 64 + lane];
    eelC = eeg[r16];

    for (int ct = 0; ct < 32; ++ct) {
        bfrag eN[2][3];
        float eelN = 0.f;
        if (ct < 31) {
#pragma unroll
            for (int db = 0; db < 2; ++db)
#pragma unroll
                for (int s = 0; s < 3; ++s)
                    eN[db][s] = epack[(((ct + 1) * 2 + db) * 3 + s) * 64 + lane];
            eelN = eeg[(ct + 1) * 16 + r16];
        }

        ffrag acc = (ffrag){0.f, 0.f, 0.f, 0.f};
#pragma unroll
        for (int db = 0; db < 2; ++db)
#pragma unroll
            for (int p = 0; p < 6; ++p)
                acc = __builtin_amdgcn_mfma_f32_16x16x32_bf16(
                    xf[db][PI[p]], eC[db][PJ[p]], acc, 0, 0, 0);

        const int kc = ct * 16 + r16;
#pragma unroll
        for (int rg = 0; rg < 4; ++rg) {
            const float dist = fmaf(-2.f, acc[rg], eelC);
            if (dist < best[rg]) { best[rg] = dist; bestk[rg] = kc; }
        }

#pragma unroll
        for (int db = 0; db < 2; ++db)
#pragma unroll
            for (int s = 0; s < 3; ++s)
                eC[db][s] = eN[db][s];
        eelC = eelN;
    }

    // ---- cross-lane argmin over each 16-lane code group ----
#pragma unroll
    for (int rg = 0; rg < 4; ++rg) {
        float b = best[rg];
        int k = bestk[rg];
#pragma unroll
        for (int m = 1; m < 16; m <<= 1) {
            const float ob = __shfl_xor(b, m, 64);
            const int ok = __shfl_xor(k, m, 64);
            if (ob < b || (ob == b && ok < k)) { b = ob; k = ok; }
        }
        bestk[rg] = k;
    }

    // quad leaders publish per-row argmin (same-wave DS ops are in-order;
    // only this wave reads its sBK slice -> no block barrier needed)
    if (r16 == 0) {
        float* crep = counts_rep + rep * K_CODES;
#pragma unroll
        for (int rg = 0; rg < 4; ++rg) {
            const int v = quad * 4 + rg;
            const int k = bestk[rg];
            sBK[wv * 16 + v] = k;
            idx[v0 + v] = k;
            atomicAdd(&crep[k], 1.0f);
        }
    }

    // ---- full one-hot rows from registers: 16 rows x 4 x 512B stores ----
#pragma unroll 4
    for (int v = 0; v < 16; ++v) {
        const int bk = sBK[wv * 16 + v];
        float* rowp = enc + (v0 + v) * (size_t)K_CODES;
#pragma unroll
        for (int part = 0; part < 4; ++part) {
            const int c0 = part * 128 + lane * 2;
            float2 val;
            val.x = (c0 == bk) ? 1.0f : 0.0f;
            val.y = (c0 + 1 == bk) ? 1.0f : 0.0f;
            *reinterpret_cast<float2*>(rowp + c0) = val;
        }
    }

    // ---- dw: reconstruct x exactly from splits, atomics into replica ----
    {
        const int myk = sBK[wv * 16 + r16];
        float* dwr = dwrep + ((size_t)rep * K_CODES + myk) * DIM;
#pragma unroll
        for (int db = 0; db < 2; ++db)
#pragma unroll
            for (int j = 0; j < 8; ++j) {
                const int d = db * 32 + quad * 8 + j;
                const float val =
                    (b2f(xf[db][0][j]) + b2f(xf[db][1][j])) + b2f(xf[db][2][j]);
                atomicAdd(&dwr[d], val);
            }
    }
}

// ---------------------------------------------------------------------------
// emaA: counts replica-reduce + EMA cluster size + Laplace + perplexity.
// ---------------------------------------------------------------------------
__global__ __launch_bounds__(512) void emaA_kernel(
    const float* __restrict__ counts_rep,
    const float* __restrict__ ema_cs,
    float* __restrict__ csbuf,
    float* __restrict__ perp_out)
{
    __shared__ float red[K_CODES];
    const int k = threadIdx.x;
    float cnt = 0.f;
#pragma unroll
    for (int r = 0; r < NREP; ++r) cnt += counts_rep[r * K_CODES + k];
    float cs = ema_cs[k] * 0.99f + 0.01f * cnt;

    red[k] = cs;
    __syncthreads();
    for (int s = K_CODES / 2; s > 0; s >>= 1) {
        if (k < s) red[k] += red[k + s];
        __syncthreads();
    }
    const float n = red[0];
    __syncthreads();

    csbuf[k] = (cs + 1e-5f) / (n + (float)K_CODES * 1e-5f) * n;

    const float p = cnt * (1.0f / (float)N_VEC);
    red[k] = p * logf(p + 1e-10f);
    __syncthreads();
    for (int s = K_CODES / 2; s > 0; s >>= 1) {
        if (k < s) red[k] += red[k + s];
        __syncthreads();
    }
    if (k == 0) perp_out[0] = expf(-red[0]);
}

// ---------------------------------------------------------------------------
// emaB: dw replica-reduce + codebook update. 32768 (k,d) threads.
// ---------------------------------------------------------------------------
__global__ __launch_bounds__(256) void emaB_kernel(
    const float* __restrict__ dwrep,
    const float* __restrict__ ema_w,
    const float* __restrict__ csbuf,
    float* __restrict__ new_emb)
{
    const int t = blockIdx.x * 256 + threadIdx.x;   // 0..32767 = k*64+d
    const int k = t >> 6;
    float dwv = 0.f;
#pragma unroll
    for (int r = 0; r < NREP; ++r) dwv += dwrep[(r << 15) + t];
    const float v = ema_w[t] * 0.99f + 0.01f * dwv;
    new_emb[t] = v / csbuf[k];
}

// ---------------------------------------------------------------------------
// quantize: gather + straight-through + NHWC->NCHW + commitment loss.
// ---------------------------------------------------------------------------
__global__ __launch_bounds__(256) void quantize_kernel(
    const float* __restrict__ inputs,
    const int* __restrict__ idx,
    const float* __restrict__ new_emb,
    float* __restrict__ out_q,
    float* __restrict__ loss_accum)
{
    __shared__ int sIdx[64];
    __shared__ float tile[DIM][65];
    __shared__ float wsum[4];

    const int bh = blockIdx.x;
    const int b = bh >> 6, h = bh & 63;
    const int t = threadIdx.x;

    if (t < 64) sIdx[t] = idx[bh * 64 + t];
    __syncthreads();

    const float* inRow = inputs + (size_t)bh * 64 * DIM;
    const int d = t & 63;
    const int wg = t >> 6;
    float lsum = 0.f;
#pragma unroll
    for (int p = 0; p < 16; ++p) {
        const int w = wg * 16 + p;
        const float xv = inRow[w * DIM + d];
        const float qv = new_emb[sIdx[w] * DIM + d];
        const float diff = qv - xv;
        tile[d][w] = xv + diff;
        lsum = fmaf(diff, diff, lsum);
    }
    __syncthreads();

    const int w2 = t & 63;
    const int dg = t >> 6;
#pragma unroll
    for (int p = 0; p < 16; ++p) {
        const int d2 = dg * 16 + p;
        out_q[(((size_t)b * DIM + d2) * 64 + h) * 64 + w2] = tile[d2][w2];
    }

    for (int off = 32; off > 0; off >>= 1) lsum += __shfl_down(lsum, off);
    if ((t & 63) == 0) wsum[t >> 6] = lsum;
    __syncthreads();
    if (t == 0) atomicAdd(loss_accum, (wsum[0] + wsum[1]) + (wsum[2] + wsum[3]));
}

__global__ void finalize_kernel(const float* __restrict__ loss_accum,
                                float* __restrict__ out_loss)
{
    out_loss[0] = 0.25f * (loss_accum[0] / 8388608.0f);
}

// ---------------------------------------------------------------------------
extern "C" void kernel_launch(void* const* d_in, const int* in_sizes, int n_in,
                              void* d_out, int out_size, void* d_ws, size_t ws_size,
                              hipStream_t stream)
{
    const float* inputs = (const float*)d_in[0];
    const float* emb_w  = (const float*)d_in[1];
    const float* ema_cs = (const float*)d_in[2];
    const float* ema_w  = (const float*)d_in[3];
    float* out = (float*)d_out;
    float* ws  = (float*)d_ws;

    // ws layout (f32 offsets):
    int*   idxbuf  = (int*)ws;              // [0, 131072)
    float* crep    = ws + 131072;           // [131072, 139264)  16x512
    float* lossac  = ws + 139264;           // [139264]
    float* csbuf   = ws + 139265;           // [139265, 139777)
    float* eebuf   = ws + 139777;           // [139777, 140289)
    float* nemb    = ws + 140289;           // [140289, 173057)
    bfrag* epack   = (bfrag*)(ws + 173060); // 192 KB, 16B-aligned

    // dw replicas (2 MB) in the not-yet-written quantized region of d_out
    // (out+16, 64B-aligned); consumed by emaB, then overwritten by quantize.
    float* dwrep = out + 16;

    hipMemsetAsync(crep, 0, (NREP * K_CODES + 1) * sizeof(float), stream);
    hipMemsetAsync(dwrep, 0, NREP * K_CODES * DIM * sizeof(float), stream);

    ee_kernel<<<1, K_CODES, 0, stream>>>(emb_w, eebuf);
    epack_kernel<<<16, 256, 0, stream>>>(emb_w, epack);

    argmin_mfma_kernel<<<N_VEC / 64, 256, 0, stream>>>(
        inputs, epack, eebuf, idxbuf, crep, dwrep, out + ENC_OFF);

    emaA_kernel<<<1, K_CODES, 0, stream>>>(crep, ema_cs, csbuf, out + PERP_OFF);
    emaB_kernel<<<K_CODES * DIM / 256, 256, 0, stream>>>(dwrep, ema_w, csbuf, nemb);

    quantize_kernel<<<32 * 64, 256, 0, stream>>>(
        inputs, idxbuf, nemb, out + Q_OFF, lossac);

    finalize_kernel<<<1, 1, 0, stream>>>(lossac, out);
}

// Round 10
// 235.002 us; speedup vs baseline: 1.9523x; 1.9523x over previous
//
#include <hip/hip_runtime.h>

#define DIM 64
#define K_CODES 512
#define N_VEC 131072
#define CREP 16
#define DREP 64
#define Q_OFF 1
#define PERP_OFF 8388609
#define ENC_OFF 8388610

using bfrag = __attribute__((ext_vector_type(8))) short;  // 8 bf16 = 4 VGPR
using ffrag = __attribute__((ext_vector_type(4))) float;  // 4 f32 acc

// Exact 3-way bf16 truncation split: x == x0 + x1 + x2.
__device__ __forceinline__ void split3(float x, short& h0, short& h1, short& h2)
{
    unsigned u0 = __float_as_uint(x);
    h0 = (short)(u0 >> 16);
    float r = x - __uint_as_float(u0 & 0xFFFF0000u);     // exact
    unsigned u1 = __float_as_uint(r);
    h1 = (short)(u1 >> 16);
    float r2 = r - __uint_as_float(u1 & 0xFFFF0000u);    // exact
    h2 = (short)(__float_as_uint(r2) >> 16);             // r2 fits bf16 exactly
}

// ---------------------------------------------------------------------------
// epack + ee fused: pre-split codebook into per-lane MFMA B-fragments
// (192 KB, L2-resident) and compute ||e||^2 per code.
// epack[((ct*2+db)*3+s)*64+lane]: code c = ct*16+(lane&15),
// d = db*32+(lane>>4)*8+0..7, split s.
// ---------------------------------------------------------------------------
__global__ __launch_bounds__(256) void epack_ee_kernel(
    const float* __restrict__ emb_w,
    bfrag* __restrict__ epack,
    float* __restrict__ ee)
{
    __shared__ float part[2][16][8];
    const int tl = threadIdx.x;
    const int t = blockIdx.x * 256 + tl;            // 0..4095
    const int lane = t & 63;
    const int db = (t >> 6) & 1;
    const int ctl = tl >> 7;                        // 0..1 (block-local)
    const int ct = t >> 7;                          // 0..31
    const int r16 = lane & 15, quad = lane >> 4;
    const int c  = ct * 16 + r16;
    const int d0 = db * 32 + quad * 8;
    const float* src = emb_w + (size_t)c * DIM + d0;

    bfrag f0, f1, f2;
    float ssum = 0.f;
#pragma unroll
    for (int j = 0; j < 8; ++j) {
        const float x = src[j];
        ssum = fmaf(x, x, ssum);
        short a, b, cc;
        split3(x, a, b, cc);
        f0[j] = a; f1[j] = b; f2[j] = cc;
    }
    const int base = (ct * 2 + db) * 3;
    epack[(base + 0) * 64 + lane] = f0;
    epack[(base + 1) * 64 + lane] = f1;
    epack[(base + 2) * 64 + lane] = f2;

    part[ctl][r16][db * 4 + quad] = ssum;
    __syncthreads();
    if (tl < 32) {
        const int cl = tl >> 4, r = tl & 15;
        float s = 0.f;
#pragma unroll
        for (int i = 0; i < 8; ++i) s += part[cl][r][i];
        ee[(blockIdx.x * 2 + cl) * 16 + r] = s;
    }
}

// ---------------------------------------------------------------------------
// enc zero-fill (268 MB, float4 grid-stride, proven ~6-7 TB/s pattern)
// + zero of the 8 MB dw replica buffer (saves a fill dispatch).
// ---------------------------------------------------------------------------
__global__ __launch_bounds__(256) void enc_zero_kernel(float* __restrict__ enc,
                                                       float* __restrict__ dwrep)
{
    const size_t nf4 = 16777215;                       // (67108864-2-2)/4
    float4* body = reinterpret_cast<float4*>(enc + 2); // 16B-aligned
    const size_t stride = (size_t)gridDim.x * 256;
    const float4 z = make_float4(0.f, 0.f, 0.f, 0.f);
    for (size_t i = (size_t)blockIdx.x * 256 + threadIdx.x; i < nf4; i += stride)
        body[i] = z;
    float4* dw4 = reinterpret_cast<float4*>(dwrep);    // out+16 -> 64B-aligned
    const size_t ndw4 = (size_t)DREP * K_CODES * DIM / 4;  // 2M f32 -> 512K f4
    for (size_t i = (size_t)blockIdx.x * 256 + threadIdx.x; i < ndw4; i += stride)
        dw4[i] = z;
    if (blockIdx.x == 0 && threadIdx.x == 0) {
        enc[0] = 0.f; enc[1] = 0.f;
        enc[67108862] = 0.f; enc[67108863] = 0.f;
    }
}

// ---------------------------------------------------------------------------
// argmin via 6-pass split-bf16 MFMA. Wave owns 32 vectors (2 row-tiles);
// block = 4 waves = 128 vectors; grid 1024 (4 blocks/CU -> 16 waves/CU TLP).
// No manual prefetch (live set ~105 VGPR; (256,4) caps at 128, no spill).
// Writes only: idx, counts into 16 replicas, sparse one-hot 1.0 stores
// (zeros pre-written by enc_zero). No LDS, no barriers.
// Tie rule: ascending-k scan + strict <, cross-lane prefers smaller k
// == numpy argmin (first minimum).
// ---------------------------------------------------------------------------
__global__ __launch_bounds__(256, 4) void argmin_mfma_kernel(
    const float* __restrict__ inputs,
    const bfrag* __restrict__ epack,
    const float* __restrict__ eeg,
    int* __restrict__ idx,
    float* __restrict__ counts_rep,
    float* __restrict__ enc)
{
    const int t = threadIdx.x;
    const int wv = t >> 6;
    const int lane = t & 63;
    const int r16 = lane & 15;
    const int quad = lane >> 4;
    const size_t v0 = (size_t)blockIdx.x * 128 + wv * 32;

    // ---- load + exact-split X into A-fragments (48 VGPRs) ----
    bfrag xf[2][2][3];
#pragma unroll
    for (int rt = 0; rt < 2; ++rt)
#pragma unroll
        for (int db = 0; db < 2; ++db) {
            const float* src = inputs + (v0 + rt * 16 + r16) * DIM + db * 32 + quad * 8;
            const float4 va = *reinterpret_cast<const float4*>(src);
            const float4 vb = *reinterpret_cast<const float4*>(src + 4);
            float vals[8] = {va.x, va.y, va.z, va.w, vb.x, vb.y, vb.z, vb.w};
            bfrag f0, f1, f2;
#pragma unroll
            for (int j = 0; j < 8; ++j) {
                short a, b, c;
                split3(vals[j], a, b, c);
                f0[j] = a; f1[j] = b; f2[j] = c;
            }
            xf[rt][db][0] = f0; xf[rt][db][1] = f1; xf[rt][db][2] = f2;
        }

    float best[2][4];
    int bestk[2][4];
#pragma unroll
    for (int a = 0; a < 2; ++a)
#pragma unroll
        for (int b = 0; b < 4; ++b) { best[a][b] = 3.4e38f; bestk[a][b] = 0; }

    constexpr int PI[6] = {0, 0, 1, 0, 2, 1};
    constexpr int PJ[6] = {0, 1, 0, 2, 0, 1};

    for (int ct = 0; ct < 32; ++ct) {
        bfrag e[2][3];
#pragma unroll
        for (int db = 0; db < 2; ++db)
#pragma unroll
            for (int s = 0; s < 3; ++s)
                e[db][s] = epack[((ct * 2 + db) * 3 + s) * 64 + lane];
        const float eel = eeg[ct * 16 + r16];

        ffrag acc[2];
        acc[0] = (ffrag){0.f, 0.f, 0.f, 0.f};
        acc[1] = (ffrag){0.f, 0.f, 0.f, 0.f};
#pragma unroll
        for (int db = 0; db < 2; ++db)
#pragma unroll
            for (int p = 0; p < 6; ++p) {
                acc[0] = __builtin_amdgcn_mfma_f32_16x16x32_bf16(
                    xf[0][db][PI[p]], e[db][PJ[p]], acc[0], 0, 0, 0);
                acc[1] = __builtin_amdgcn_mfma_f32_16x16x32_bf16(
                    xf[1][db][PI[p]], e[db][PJ[p]], acc[1], 0, 0, 0);
            }

        const int kc = ct * 16 + r16;
#pragma unroll
        for (int rt = 0; rt < 2; ++rt)
#pragma unroll
            for (int rg = 0; rg < 4; ++rg) {
                const float dist = fmaf(-2.f, acc[rt][rg], eel);
                if (dist < best[rt][rg]) { best[rt][rg] = dist; bestk[rt][rg] = kc; }
            }
    }

    // ---- cross-lane argmin over each 16-lane code group ----
#pragma unroll
    for (int rt = 0; rt < 2; ++rt)
#pragma unroll
        for (int rg = 0; rg < 4; ++rg) {
            float b = best[rt][rg];
            int k = bestk[rt][rg];
#pragma unroll
            for (int m = 1; m < 16; m <<= 1) {
                const float ob = __shfl_xor(b, m, 64);
                const int ok = __shfl_xor(k, m, 64);
                if (ob < b || (ob == b && ok < k)) { b = ob; k = ok; }
            }
            bestk[rt][rg] = k;
        }

    if (r16 == 0) {
        float* crep = counts_rep + (blockIdx.x & (CREP - 1)) * K_CODES;
#pragma unroll
        for (int rt = 0; rt < 2; ++rt)
#pragma unroll
            for (int rg = 0; rg < 4; ++rg) {
                const int v = rt * 16 + quad * 4 + rg;
                const int k = bestk[rt][rg];
                idx[v0 + v] = k;
                atomicAdd(&crep[k], 1.0f);
                enc[(v0 + v) * (size_t)K_CODES + k] = 1.0f;
            }
    }
}

// ---------------------------------------------------------------------------
// dw segment-sum into 64 replica buffers (replica = v & 63).
// Block = 256 vectors; wave handles 64; lane = d. Contiguous 256B row atomics.
// ---------------------------------------------------------------------------
__global__ __launch_bounds__(256) void dw_scatter_kernel(
    const float* __restrict__ inputs,
    const int* __restrict__ idx,
    float* __restrict__ dwrep)
{
    __shared__ int sIdx[256];
    const int t = threadIdx.x;
    const size_t vbase = (size_t)blockIdx.x * 256;
    sIdx[t] = idx[vbase + t];
    __syncthreads();
    const int w = t >> 6, lane = t & 63;
    const int v0 = w * 64;
#pragma unroll 4
    for (int j = 0; j < 64; ++j) {
        const int v = v0 + j;
        const int k = sIdx[v];
        const float xv = inputs[(vbase + v) * DIM + lane];
        atomicAdd(&dwrep[((size_t)(v & (DREP - 1)) << 15) + (k << 6) + lane], xv);
    }
}

// ---------------------------------------------------------------------------
// emaA: counts replica-reduce + EMA cluster size + Laplace + perplexity.
// ---------------------------------------------------------------------------
__global__ __launch_bounds__(512) void emaA_kernel(
    const float* __restrict__ counts_rep,
    const float* __restrict__ ema_cs,
    float* __restrict__ csbuf,
    float* __restrict__ perp_out)
{
    __shared__ float red[K_CODES];
    const int k = threadIdx.x;
    float cnt = 0.f;
#pragma unroll
    for (int r = 0; r < CREP; ++r) cnt += counts_rep[r * K_CODES + k];
    float cs = ema_cs[k] * 0.99f + 0.01f * cnt;

    red[k] = cs;
    __syncthreads();
    for (int s = K_CODES / 2; s > 0; s >>= 1) {
        if (k < s) red[k] += red[k + s];
        __syncthreads();
    }
    const float n = red[0];
    __syncthreads();

    csbuf[k] = (cs + 1e-5f) / (n + (float)K_CODES * 1e-5f) * n;

    const float p = cnt * (1.0f / (float)N_VEC);
    red[k] = p * logf(p + 1e-10f);
    __syncthreads();
    for (int s = K_CODES / 2; s > 0; s >>= 1) {
        if (k < s) red[k] += red[k + s];
        __syncthreads();
    }
    if (k == 0) perp_out[0] = expf(-red[0]);
}

// ---------------------------------------------------------------------------
// emaB: dw replica-reduce + codebook update. 32768 (k,d) threads.
// ---------------------------------------------------------------------------
__global__ __launch_bounds__(256) void emaB_kernel(
    const float* __restrict__ dwrep,
    const float* __restrict__ ema_w,
    const float* __restrict__ csbuf,
    float* __restrict__ new_emb)
{
    const int t = blockIdx.x * 256 + threadIdx.x;   // 0..32767 = k*64+d
    const int k = t >> 6;
    float dwv = 0.f;
#pragma unroll
    for (int r = 0; r < DREP; ++r) dwv += dwrep[((size_t)r << 15) + t];
    const float v = ema_w[t] * 0.99f + 0.01f * dwv;
    new_emb[t] = v / csbuf[k];
}

// ---------------------------------------------------------------------------
// quantize: gather + straight-through + NHWC->NCHW + commitment loss.
// ---------------------------------------------------------------------------
__global__ __launch_bounds__(256) void quantize_kernel(
    const float* __restrict__ inputs,
    const int* __restrict__ idx,
    const float* __restrict__ new_emb,
    float* __restrict__ out_q,
    float* __restrict__ loss_accum)
{
    __shared__ int sIdx[64];
    __shared__ float tile[DIM][65];
    __shared__ float wsum[4];

    const int bh = blockIdx.x;
    const int b = bh >> 6, h = bh & 63;
    const int t = threadIdx.x;

    if (t < 64) sIdx[t] = idx[bh * 64 + t];
    __syncthreads();

    const float* inRow = inputs + (size_t)bh * 64 * DIM;
    const int d = t & 63;
    const int wg = t >> 6;
    float lsum = 0.f;
#pragma unroll
    for (int p = 0; p < 16; ++p) {
        const int w = wg * 16 + p;
        const float xv = inRow[w * DIM + d];
        const float qv = new_emb[sIdx[w] * DIM + d];
        const float diff = qv - xv;
        tile[d][w] = xv + diff;
        lsum = fmaf(diff, diff, lsum);
    }
    __syncthreads();

    const int w2 = t & 63;
    const int dg = t >> 6;
#pragma unroll
    for (int p = 0; p < 16; ++p) {
        const int d2 = dg * 16 + p;
        out_q[(((size_t)b * DIM + d2) * 64 + h) * 64 + w2] = tile[d2][w2];
    }

    for (int off = 32; off > 0; off >>= 1) lsum += __shfl_down(lsum, off);
    if ((t & 63) == 0) wsum[t >> 6] = lsum;
    __syncthreads();
    if (t == 0) atomicAdd(loss_accum, (wsum[0] + wsum[1]) + (wsum[2] + wsum[3]));
}

__global__ void finalize_kernel(const float* __restrict__ loss_accum,
                                float* __restrict__ out_loss)
{
    out_loss[0] = 0.25f * (loss_accum[0] / 8388608.0f);
}

// ---------------------------------------------------------------------------
extern "C" void kernel_launch(void* const* d_in, const int* in_sizes, int n_in,
                              void* d_out, int out_size, void* d_ws, size_t ws_size,
                              hipStream_t stream)
{
    const float* inputs = (const float*)d_in[0];
    const float* emb_w  = (const float*)d_in[1];
    const float* ema_cs = (const float*)d_in[2];
    const float* ema_w  = (const float*)d_in[3];
    float* out = (float*)d_out;
    float* ws  = (float*)d_ws;

    // ws layout (f32 offsets):
    int*   idxbuf  = (int*)ws;              // [0, 131072)
    float* crep    = ws + 131072;           // [131072, 139264)  16x512
    float* lossac  = ws + 139264;           // [139264]
    float* csbuf   = ws + 139265;           // [139265, 139777)
    float* eebuf   = ws + 139777;           // [139777, 140289)
    float* nemb    = ws + 140289;           // [140289, 173057)
    bfrag* epack   = (bfrag*)(ws + 173060); // 192 KB, 16B-aligned

    // dw replicas (8 MB) in the not-yet-written quantized region of d_out
    // (out+16 -> 64B-aligned); consumed by emaB, then overwritten by quantize.
    float* dwrep = out + 16;

    hipMemsetAsync(crep, 0, (CREP * K_CODES + 1) * sizeof(float), stream);

    epack_ee_kernel<<<16, 256, 0, stream>>>(emb_w, epack, eebuf);

    enc_zero_kernel<<<2048, 256, 0, stream>>>(out + ENC_OFF, dwrep);

    argmin_mfma_kernel<<<N_VEC / 128, 256, 0, stream>>>(
        inputs, epack, eebuf, idxbuf, crep, out + ENC_OFF);

    dw_scatter_kernel<<<N_VEC / 256, 256, 0, stream>>>(inputs, idxbuf, dwrep);

    emaA_kernel<<<1, K_CODES, 0, stream>>>(crep, ema_cs, csbuf, out + PERP_OFF);
    emaB_kernel<<<K_CODES * DIM / 256, 256, 0, stream>>>(dwrep, ema_w, csbuf, nemb);

    quantize_kernel<<<32 * 64, 256, 0, stream>>>(
        inputs, idxbuf, nemb, out + Q_OFF, lossac);

    finalize_kernel<<<1, 1, 0, stream>>>(lossac, out);
}

// Round 11
// 216.712 us; speedup vs baseline: 2.1170x; 1.0844x over previous
//
#include <hip/hip_runtime.h>

#define DIM 64
#define K_CODES 512
#define N_VEC 131072
#define CREP 16
#define DREP 64
#define Q_OFF 1
#define PERP_OFF 8388609
#define ENC_OFF 8388610

using bfrag = __attribute__((ext_vector_type(8))) short;  // 8 bf16 = 4 VGPR
using ffrag = __attribute__((ext_vector_type(4))) float;  // 4 f32 acc

// Exact 3-way bf16 truncation split: x == x0 + x1 + x2.
__device__ __forceinline__ void split3(float x, short& h0, short& h1, short& h2)
{
    unsigned u0 = __float_as_uint(x);
    h0 = (short)(u0 >> 16);
    float r = x - __uint_as_float(u0 & 0xFFFF0000u);     // exact
    unsigned u1 = __float_as_uint(r);
    h1 = (short)(u1 >> 16);
    float r2 = r - __uint_as_float(u1 & 0xFFFF0000u);    // exact
    h2 = (short)(__float_as_uint(r2) >> 16);             // r2 fits bf16 exactly
}

// ---------------------------------------------------------------------------
// epack + ee fused, plus zeroing of crep/lossac (removes one memset dispatch).
// epack[((ct*2+db)*3+s)*64+lane]: code c = ct*16+(lane&15),
// d = db*32+(lane>>4)*8+0..7, split s. 192 KB, L2-resident.
// ---------------------------------------------------------------------------
__global__ __launch_bounds__(256) void epack_ee_kernel(
    const float* __restrict__ emb_w,
    bfrag* __restrict__ epack,
    float* __restrict__ ee,
    float* __restrict__ crep,
    float* __restrict__ lossac)
{
    __shared__ float part[2][16][8];
    const int tl = threadIdx.x;
    const int t = blockIdx.x * 256 + tl;            // 0..4095
    const int lane = t & 63;
    const int db = (t >> 6) & 1;
    const int ctl = tl >> 7;                        // 0..1 (block-local)
    const int ct = t >> 7;                          // 0..31
    const int r16 = lane & 15, quad = lane >> 4;
    const int c  = ct * 16 + r16;
    const int d0 = db * 32 + quad * 8;
    const float* src = emb_w + (size_t)c * DIM + d0;

    // zero counts replicas (16x512) + loss accumulator
    crep[t] = 0.f;
    crep[4096 + t] = 0.f;
    if (t == 0) lossac[0] = 0.f;

    bfrag f0, f1, f2;
    float ssum = 0.f;
#pragma unroll
    for (int j = 0; j < 8; ++j) {
        const float x = src[j];
        ssum = fmaf(x, x, ssum);
        short a, b, cc;
        split3(x, a, b, cc);
        f0[j] = a; f1[j] = b; f2[j] = cc;
    }
    const int base = (ct * 2 + db) * 3;
    epack[(base + 0) * 64 + lane] = f0;
    epack[(base + 1) * 64 + lane] = f1;
    epack[(base + 2) * 64 + lane] = f2;

    part[ctl][r16][db * 4 + quad] = ssum;
    __syncthreads();
    if (tl < 32) {
        const int cl = tl >> 4, r = tl & 15;
        float s = 0.f;
#pragma unroll
        for (int i = 0; i < 8; ++i) s += part[cl][r][i];
        ee[(blockIdx.x * 2 + cl) * 16 + r] = s;
    }
}

// ---------------------------------------------------------------------------
// argmin via 6-pass split-bf16 MFMA. Wave owns 32 vectors (2 row-tiles);
// block = 4 waves = 128 vectors; grid 1024 (4 blocks/CU TLP).
// Writes ONLY idx + counts into 16 replicas. No enc stores, no LDS barriers.
// Tie rule: ascending-k scan + strict <, cross-lane prefers smaller k
// == numpy argmin (first minimum).
// ---------------------------------------------------------------------------
__global__ __launch_bounds__(256, 4) void argmin_mfma_kernel(
    const float* __restrict__ inputs,
    const bfrag* __restrict__ epack,
    const float* __restrict__ eeg,
    int* __restrict__ idx,
    float* __restrict__ counts_rep)
{
    const int t = threadIdx.x;
    const int lane = t & 63;
    const int r16 = lane & 15;
    const int quad = lane >> 4;
    const size_t v0 = (size_t)blockIdx.x * 128 + (t >> 6) * 32;

    // ---- load + exact-split X into A-fragments (48 VGPRs) ----
    bfrag xf[2][2][3];
#pragma unroll
    for (int rt = 0; rt < 2; ++rt)
#pragma unroll
        for (int db = 0; db < 2; ++db) {
            const float* src = inputs + (v0 + rt * 16 + r16) * DIM + db * 32 + quad * 8;
            const float4 va = *reinterpret_cast<const float4*>(src);
            const float4 vb = *reinterpret_cast<const float4*>(src + 4);
            float vals[8] = {va.x, va.y, va.z, va.w, vb.x, vb.y, vb.z, vb.w};
            bfrag f0, f1, f2;
#pragma unroll
            for (int j = 0; j < 8; ++j) {
                short a, b, c;
                split3(vals[j], a, b, c);
                f0[j] = a; f1[j] = b; f2[j] = c;
            }
            xf[rt][db][0] = f0; xf[rt][db][1] = f1; xf[rt][db][2] = f2;
        }

    float best[2][4];
    int bestk[2][4];
#pragma unroll
    for (int a = 0; a < 2; ++a)
#pragma unroll
        for (int b = 0; b < 4; ++b) { best[a][b] = 3.4e38f; bestk[a][b] = 0; }

    constexpr int PI[6] = {0, 0, 1, 0, 2, 1};
    constexpr int PJ[6] = {0, 1, 0, 2, 0, 1};

    for (int ct = 0; ct < 32; ++ct) {
        bfrag e[2][3];
#pragma unroll
        for (int db = 0; db < 2; ++db)
#pragma unroll
            for (int s = 0; s < 3; ++s)
                e[db][s] = epack[((ct * 2 + db) * 3 + s) * 64 + lane];
        const float eel = eeg[ct * 16 + r16];

        ffrag acc[2];
        acc[0] = (ffrag){0.f, 0.f, 0.f, 0.f};
        acc[1] = (ffrag){0.f, 0.f, 0.f, 0.f};
#pragma unroll
        for (int db = 0; db < 2; ++db)
#pragma unroll
            for (int p = 0; p < 6; ++p) {
                acc[0] = __builtin_amdgcn_mfma_f32_16x16x32_bf16(
                    xf[0][db][PI[p]], e[db][PJ[p]], acc[0], 0, 0, 0);
                acc[1] = __builtin_amdgcn_mfma_f32_16x16x32_bf16(
                    xf[1][db][PI[p]], e[db][PJ[p]], acc[1], 0, 0, 0);
            }

        const int kc = ct * 16 + r16;
#pragma unroll
        for (int rt = 0; rt < 2; ++rt)
#pragma unroll
            for (int rg = 0; rg < 4; ++rg) {
                const float dist = fmaf(-2.f, acc[rt][rg], eel);
                if (dist < best[rt][rg]) { best[rt][rg] = dist; bestk[rt][rg] = kc; }
            }
    }

    // ---- cross-lane argmin over each 16-lane code group ----
#pragma unroll
    for (int rt = 0; rt < 2; ++rt)
#pragma unroll
        for (int rg = 0; rg < 4; ++rg) {
            float b = best[rt][rg];
            int k = bestk[rt][rg];
#pragma unroll
            for (int m = 1; m < 16; m <<= 1) {
                const float ob = __shfl_xor(b, m, 64);
                const int ok = __shfl_xor(k, m, 64);
                if (ob < b || (ob == b && ok < k)) { b = ob; k = ok; }
            }
            bestk[rt][rg] = k;
        }

    if (r16 == 0) {
        float* crep = counts_rep + (blockIdx.x & (CREP - 1)) * K_CODES;
#pragma unroll
        for (int rt = 0; rt < 2; ++rt)
#pragma unroll
            for (int rg = 0; rg < 4; ++rg) {
                const int v = rt * 16 + quad * 4 + rg;
                const int k = bestk[rt][rg];
                idx[v0 + v] = k;
                atomicAdd(&crep[k], 1.0f);
            }
    }
}

// ---------------------------------------------------------------------------
// enc_write: the ONE full pass over the 268 MB one-hot output. Grid-stride
// float4 stores (the 6.7-7.0 TB/s fill pattern), each component computed as
// (col == idx[row]). Also zeroes the 8 MB dw replica buffer (saves a fill).
// enc base is 8B-aligned: float4 body at enc+2, 4 scalar edge elements.
// ---------------------------------------------------------------------------
__global__ __launch_bounds__(256) void enc_write_kernel(
    const int* __restrict__ idx,
    float* __restrict__ enc,
    float* __restrict__ dwrep)
{
    const size_t nf4 = 16777215;                       // (67108864-4)/4
    float4* body = reinterpret_cast<float4*>(enc + 2); // 16B-aligned
    const size_t stride = (size_t)gridDim.x * 256;

    for (size_t g = (size_t)blockIdx.x * 256 + threadIdx.x; g < nf4; g += stride) {
        const size_t e0 = 4 * g + 2;                   // element index of .x
        const int r0 = (int)(e0 >> 9);
        const int r1 = (int)((e0 + 3) >> 9);
        const int i0 = idx[r0];
        const int i1 = (r1 != r0) ? idx[r1] : i0;
        float4 v;
        v.x = ((int)(e0 & 511) == i0) ? 1.f : 0.f;
        v.y = ((int)((e0 + 1) & 511) == (((e0 + 1) >> 9) == (size_t)r0 ? i0 : i1)) ? 1.f : 0.f;
        v.z = ((int)((e0 + 2) & 511) == (((e0 + 2) >> 9) == (size_t)r0 ? i0 : i1)) ? 1.f : 0.f;
        v.w = ((int)((e0 + 3) & 511) == (((e0 + 3) >> 9) == (size_t)r0 ? i0 : i1)) ? 1.f : 0.f;
        body[g] = v;
    }

    // zero dw replicas (8 MB), 16B-aligned (out+16)
    float4* dw4 = reinterpret_cast<float4*>(dwrep);
    const size_t ndw4 = (size_t)DREP * K_CODES * DIM / 4;
    const float4 z = make_float4(0.f, 0.f, 0.f, 0.f);
    for (size_t i = (size_t)blockIdx.x * 256 + threadIdx.x; i < ndw4; i += stride)
        dw4[i] = z;

    if (blockIdx.x == 0 && threadIdx.x == 0) {
        const int k0 = idx[0];
        enc[0] = (k0 == 0) ? 1.f : 0.f;
        enc[1] = (k0 == 1) ? 1.f : 0.f;
        const int kL = idx[N_VEC - 1];
        enc[67108862] = (kL == 510) ? 1.f : 0.f;
        enc[67108863] = (kL == 511) ? 1.f : 0.f;
    }
}

// ---------------------------------------------------------------------------
// dw segment-sum into 64 replica buffers (replica = v & 63).
// Block = 256 vectors; wave handles 64; lane = d. Contiguous 256B row atomics.
// ---------------------------------------------------------------------------
__global__ __launch_bounds__(256) void dw_scatter_kernel(
    const float* __restrict__ inputs,
    const int* __restrict__ idx,
    float* __restrict__ dwrep)
{
    __shared__ int sIdx[256];
    const int t = threadIdx.x;
    const size_t vbase = (size_t)blockIdx.x * 256;
    sIdx[t] = idx[vbase + t];
    __syncthreads();
    const int w = t >> 6, lane = t & 63;
    const int v0 = w * 64;
#pragma unroll 4
    for (int j = 0; j < 64; ++j) {
        const int v = v0 + j;
        const int k = sIdx[v];
        const float xv = inputs[(vbase + v) * DIM + lane];
        atomicAdd(&dwrep[((size_t)(v & (DREP - 1)) << 15) + (k << 6) + lane], xv);
    }
}

// ---------------------------------------------------------------------------
// emaA: counts replica-reduce + EMA cluster size + Laplace + perplexity.
// ---------------------------------------------------------------------------
__global__ __launch_bounds__(512) void emaA_kernel(
    const float* __restrict__ counts_rep,
    const float* __restrict__ ema_cs,
    float* __restrict__ csbuf,
    float* __restrict__ perp_out)
{
    __shared__ float red[K_CODES];
    const int k = threadIdx.x;
    float cnt = 0.f;
#pragma unroll
    for (int r = 0; r < CREP; ++r) cnt += counts_rep[r * K_CODES + k];
    float cs = ema_cs[k] * 0.99f + 0.01f * cnt;

    red[k] = cs;
    __syncthreads();
    for (int s = K_CODES / 2; s > 0; s >>= 1) {
        if (k < s) red[k] += red[k + s];
        __syncthreads();
    }
    const float n = red[0];
    __syncthreads();

    csbuf[k] = (cs + 1e-5f) / (n + (float)K_CODES * 1e-5f) * n;

    const float p = cnt * (1.0f / (float)N_VEC);
    red[k] = p * logf(p + 1e-10f);
    __syncthreads();
    for (int s = K_CODES / 2; s > 0; s >>= 1) {
        if (k < s) red[k] += red[k + s];
        __syncthreads();
    }
    if (k == 0) perp_out[0] = expf(-red[0]);
}

// ---------------------------------------------------------------------------
// emaB: dw replica-reduce + codebook update. 32768 (k,d) threads.
// ---------------------------------------------------------------------------
__global__ __launch_bounds__(256) void emaB_kernel(
    const float* __restrict__ dwrep,
    const float* __restrict__ ema_w,
    const float* __restrict__ csbuf,
    float* __restrict__ new_emb)
{
    const int t = blockIdx.x * 256 + threadIdx.x;   // 0..32767 = k*64+d
    const int k = t >> 6;
    float dwv = 0.f;
#pragma unroll
    for (int r = 0; r < DREP; ++r) dwv += dwrep[((size_t)r << 15) + t];
    const float v = ema_w[t] * 0.99f + 0.01f * dwv;
    new_emb[t] = v / csbuf[k];
}

// ---------------------------------------------------------------------------
// quantize: gather + straight-through + NHWC->NCHW + commitment loss.
// ---------------------------------------------------------------------------
__global__ __launch_bounds__(256) void quantize_kernel(
    const float* __restrict__ inputs,
    const int* __restrict__ idx,
    const float* __restrict__ new_emb,
    float* __restrict__ out_q,
    float* __restrict__ loss_accum)
{
    __shared__ int sIdx[64];
    __shared__ float tile[DIM][65];
    __shared__ float wsum[4];

    const int bh = blockIdx.x;
    const int b = bh >> 6, h = bh & 63;
    const int t = threadIdx.x;

    if (t < 64) sIdx[t] = idx[bh * 64 + t];
    __syncthreads();

    const float* inRow = inputs + (size_t)bh * 64 * DIM;
    const int d = t & 63;
    const int wg = t >> 6;
    float lsum = 0.f;
#pragma unroll
    for (int p = 0; p < 16; ++p) {
        const int w = wg * 16 + p;
        const float xv = inRow[w * DIM + d];
        const float qv = new_emb[sIdx[w] * DIM + d];
        const float diff = qv - xv;
        tile[d][w] = xv + diff;
        lsum = fmaf(diff, diff, lsum);
    }
    __syncthreads();

    const int w2 = t & 63;
    const int dg = t >> 6;
#pragma unroll
    for (int p = 0; p < 16; ++p) {
        const int d2 = dg * 16 + p;
        out_q[(((size_t)b * DIM + d2) * 64 + h) * 64 + w2] = tile[d2][w2];
    }

    for (int off = 32; off > 0; off >>= 1) lsum += __shfl_down(lsum, off);
    if ((t & 63) == 0) wsum[t >> 6] = lsum;
    __syncthreads();
    if (t == 0) atomicAdd(loss_accum, (wsum[0] + wsum[1]) + (wsum[2] + wsum[3]));
}

__global__ void finalize_kernel(const float* __restrict__ loss_accum,
                                float* __restrict__ out_loss)
{
    out_loss[0] = 0.25f * (loss_accum[0] / 8388608.0f);
}

// ---------------------------------------------------------------------------
extern "C" void kernel_launch(void* const* d_in, const int* in_sizes, int n_in,
                              void* d_out, int out_size, void* d_ws, size_t ws_size,
                              hipStream_t stream)
{
    const float* inputs = (const float*)d_in[0];
    const float* emb_w  = (const float*)d_in[1];
    const float* ema_cs = (const float*)d_in[2];
    const float* ema_w  = (const float*)d_in[3];
    float* out = (float*)d_out;
    float* ws  = (float*)d_ws;

    // ws layout (f32 offsets):
    int*   idxbuf  = (int*)ws;              // [0, 131072)
    float* crep    = ws + 131072;           // [131072, 139264)  16x512
    float* lossac  = ws + 139264;           // [139264]
    float* csbuf   = ws + 139265;           // [139265, 139777)
    float* eebuf   = ws + 139777;           // [139777, 140289)
    float* nemb    = ws + 140289;           // [140289, 173057)
    bfrag* epack   = (bfrag*)(ws + 173060); // 192 KB, 16B-aligned

    // dw replicas (8 MB) in the not-yet-written quantized region of d_out
    // (out+16 -> 64B-aligned); consumed by emaB, then overwritten by quantize.
    float* dwrep = out + 16;

    epack_ee_kernel<<<16, 256, 0, stream>>>(emb_w, epack, eebuf, crep, lossac);

    argmin_mfma_kernel<<<N_VEC / 128, 256, 0, stream>>>(
        inputs, epack, eebuf, idxbuf, crep);

    enc_write_kernel<<<2048, 256, 0, stream>>>(idxbuf, out + ENC_OFF, dwrep);

    dw_scatter_kernel<<<N_VEC / 256, 256, 0, stream>>>(inputs, idxbuf, dwrep);

    emaA_kernel<<<1, K_CODES, 0, stream>>>(crep, ema_cs, csbuf, out + PERP_OFF);
    emaB_kernel<<<K_CODES * DIM / 256, 256, 0, stream>>>(dwrep, ema_w, csbuf, nemb);

    quantize_kernel<<<32 * 64, 256, 0, stream>>>(
        inputs, idxbuf, nemb, out + Q_OFF, lossac);

    finalize_kernel<<<1, 1, 0, stream>>>(lossac, out);
}

// Round 12
// 184.340 us; speedup vs baseline: 2.4888x; 1.1756x over previous
//
#include <hip/hip_runtime.h>

#define DIM 64
#define K_CODES 512
#define N_VEC 131072
#define CREP 16
#define DREP 64
#define Q_OFF 1
#define PERP_OFF 8388609
#define ENC_OFF 8388610

#define DW_BLOCKS 512
#define ENC_BLOCKS 1280

using bfrag = __attribute__((ext_vector_type(8))) short;  // 8 bf16 = 4 VGPR
using ffrag = __attribute__((ext_vector_type(4))) float;  // 4 f32 acc

// Exact 3-way bf16 truncation split: x == x0 + x1 + x2.
__device__ __forceinline__ void split3(float x, short& h0, short& h1, short& h2)
{
    unsigned u0 = __float_as_uint(x);
    h0 = (short)(u0 >> 16);
    float r = x - __uint_as_float(u0 & 0xFFFF0000u);     // exact
    unsigned u1 = __float_as_uint(r);
    h1 = (short)(u1 >> 16);
    float r2 = r - __uint_as_float(u1 & 0xFFFF0000u);    // exact
    h2 = (short)(__float_as_uint(r2) >> 16);             // r2 fits bf16 exactly
}

// ---------------------------------------------------------------------------
// epack + ee fused, plus zeroing of crep/lossac.
// epack[((ct*2+db)*3+s)*64+lane]: code c = ct*16+(lane&15),
// d = db*32+(lane>>4)*8+0..7, split s. 192 KB, L2-resident.
// ---------------------------------------------------------------------------
__global__ __launch_bounds__(256) void epack_ee_kernel(
    const float* __restrict__ emb_w,
    bfrag* __restrict__ epack,
    float* __restrict__ ee,
    float* __restrict__ crep,
    float* __restrict__ lossac)
{
    __shared__ float part[2][16][8];
    const int tl = threadIdx.x;
    const int t = blockIdx.x * 256 + tl;            // 0..4095
    const int lane = t & 63;
    const int db = (t >> 6) & 1;
    const int ctl = tl >> 7;                        // 0..1 (block-local)
    const int ct = t >> 7;                          // 0..31
    const int r16 = lane & 15, quad = lane >> 4;
    const int c  = ct * 16 + r16;
    const int d0 = db * 32 + quad * 8;
    const float* src = emb_w + (size_t)c * DIM + d0;

    crep[t] = 0.f;
    crep[4096 + t] = 0.f;
    if (t == 0) lossac[0] = 0.f;

    bfrag f0, f1, f2;
    float ssum = 0.f;
#pragma unroll
    for (int j = 0; j < 8; ++j) {
        const float x = src[j];
        ssum = fmaf(x, x, ssum);
        short a, b, cc;
        split3(x, a, b, cc);
        f0[j] = a; f1[j] = b; f2[j] = cc;
    }
    const int base = (ct * 2 + db) * 3;
    epack[(base + 0) * 64 + lane] = f0;
    epack[(base + 1) * 64 + lane] = f1;
    epack[(base + 2) * 64 + lane] = f2;

    part[ctl][r16][db * 4 + quad] = ssum;
    __syncthreads();
    if (tl < 32) {
        const int cl = tl >> 4, r = tl & 15;
        float s = 0.f;
#pragma unroll
        for (int i = 0; i < 8; ++i) s += part[cl][r][i];
        ee[(blockIdx.x * 2 + cl) * 16 + r] = s;
    }
}

// ---------------------------------------------------------------------------
// argmin via 6-pass split-bf16 MFMA. Wave owns 64 vectors (4 row-tiles);
// block = 4 waves = 256 vectors; grid 512 (2 blocks/CU co-resident).
// Live set ~185 VGPR, (256,2) caps at 256 -> no spill. 393 MB L2 epack
// traffic (half of the 32-vec version). Prologue zeroes its 16 KB slice of
// dwrep (plain stores; consumed by the NEXT kernel -> stream-ordered).
// Writes only idx + counts into 16 replicas.
// Tie rule: ascending-k scan + strict <, cross-lane prefers smaller k
// == numpy argmin (first minimum).
// ---------------------------------------------------------------------------
__global__ __launch_bounds__(256, 2) void argmin_mfma_kernel(
    const float* __restrict__ inputs,
    const bfrag* __restrict__ epack,
    const float* __restrict__ eeg,
    int* __restrict__ idx,
    float* __restrict__ counts_rep,
    float* __restrict__ dwrep)
{
    const int t = threadIdx.x;
    const int lane = t & 63;
    const int r16 = lane & 15;
    const int quad = lane >> 4;
    const size_t v0 = (size_t)blockIdx.x * 256 + (t >> 6) * 64;

    // ---- zero this block's 16 KB slice of dwrep (8 MB / 512 blocks) ----
    {
        float4* z4 = reinterpret_cast<float4*>(dwrep) + (size_t)blockIdx.x * 1024;
        const float4 z = make_float4(0.f, 0.f, 0.f, 0.f);
#pragma unroll
        for (int i = 0; i < 4; ++i) z4[i * 256 + t] = z;
    }

    // ---- load + exact-split X into A-fragments (96 VGPRs) ----
    bfrag xf[4][2][3];
#pragma unroll
    for (int rt = 0; rt < 4; ++rt)
#pragma unroll
        for (int db = 0; db < 2; ++db) {
            const float* src = inputs + (v0 + rt * 16 + r16) * DIM + db * 32 + quad * 8;
            const float4 va = *reinterpret_cast<const float4*>(src);
            const float4 vb = *reinterpret_cast<const float4*>(src + 4);
            float vals[8] = {va.x, va.y, va.z, va.w, vb.x, vb.y, vb.z, vb.w};
            bfrag f0, f1, f2;
#pragma unroll
            for (int j = 0; j < 8; ++j) {
                short a, b, c;
                split3(vals[j], a, b, c);
                f0[j] = a; f1[j] = b; f2[j] = c;
            }
            xf[rt][db][0] = f0; xf[rt][db][1] = f1; xf[rt][db][2] = f2;
        }

    float best[4][4];
    int bestk[4][4];
#pragma unroll
    for (int a = 0; a < 4; ++a)
#pragma unroll
        for (int b = 0; b < 4; ++b) { best[a][b] = 3.4e38f; bestk[a][b] = 0; }

    constexpr int PI[6] = {0, 0, 1, 0, 2, 1};
    constexpr int PJ[6] = {0, 1, 0, 2, 0, 1};

#pragma unroll 2
    for (int ct = 0; ct < 32; ++ct) {
        bfrag e[2][3];
#pragma unroll
        for (int db = 0; db < 2; ++db)
#pragma unroll
            for (int s = 0; s < 3; ++s)
                e[db][s] = epack[((ct * 2 + db) * 3 + s) * 64 + lane];
        const float eel = eeg[ct * 16 + r16];

        ffrag acc[4];
#pragma unroll
        for (int rt = 0; rt < 4; ++rt) acc[rt] = (ffrag){0.f, 0.f, 0.f, 0.f};

#pragma unroll
        for (int db = 0; db < 2; ++db)
#pragma unroll
            for (int p = 0; p < 6; ++p)
#pragma unroll
                for (int rt = 0; rt < 4; ++rt)
                    acc[rt] = __builtin_amdgcn_mfma_f32_16x16x32_bf16(
                        xf[rt][db][PI[p]], e[db][PJ[p]], acc[rt], 0, 0, 0);

        const int kc = ct * 16 + r16;
#pragma unroll
        for (int rt = 0; rt < 4; ++rt)
#pragma unroll
            for (int rg = 0; rg < 4; ++rg) {
                const float dist = fmaf(-2.f, acc[rt][rg], eel);
                if (dist < best[rt][rg]) { best[rt][rg] = dist; bestk[rt][rg] = kc; }
            }
    }

    // ---- cross-lane argmin over each 16-lane code group ----
#pragma unroll
    for (int rt = 0; rt < 4; ++rt)
#pragma unroll
        for (int rg = 0; rg < 4; ++rg) {
            float b = best[rt][rg];
            int k = bestk[rt][rg];
#pragma unroll
            for (int m = 1; m < 16; m <<= 1) {
                const float ob = __shfl_xor(b, m, 64);
                const int ok = __shfl_xor(k, m, 64);
                if (ob < b || (ob == b && ok < k)) { b = ob; k = ok; }
            }
            bestk[rt][rg] = k;
        }

    if (r16 == 0) {
        float* crep = counts_rep + (blockIdx.x & (CREP - 1)) * K_CODES;
#pragma unroll
        for (int rt = 0; rt < 4; ++rt)
#pragma unroll
            for (int rg = 0; rg < 4; ++rg) {
                const int v = rt * 16 + quad * 4 + rg;
                const int k = bestk[rt][rg];
                idx[v0 + v] = k;
                atomicAdd(&crep[k], 1.0f);
            }
    }
}

// ---------------------------------------------------------------------------
// Uber kernel: enc one-hot full write (1280 blocks, grid-stride float4 at
// the measured ~6.9 TB/s fill pattern) CONCURRENT with dw segment-sum
// (512 blocks, 64-replica contiguous row atomics). Both depend only on idx;
// 458K threads co-resident (< 524K capacity) -> true overlap of the
// write-BW-bound and atomic-latency-bound phases.
// ---------------------------------------------------------------------------
__global__ __launch_bounds__(256) void encdw_kernel(
    const float* __restrict__ inputs,
    const int* __restrict__ idx,
    float* __restrict__ enc,
    float* __restrict__ dwrep)
{
    const int bid = blockIdx.x;
    const int t = threadIdx.x;

    if (bid < DW_BLOCKS) {
        // ---------------- dw scatter: 256 vectors per block ----------------
        __shared__ int sIdx[256];
        const size_t vbase = (size_t)bid * 256;
        sIdx[t] = idx[vbase + t];
        __syncthreads();
        const int w = t >> 6, lane = t & 63;
        const int v0 = w * 64;
#pragma unroll 4
        for (int j = 0; j < 64; ++j) {
            const int v = v0 + j;
            const int k = sIdx[v];
            const float xv = inputs[(vbase + v) * DIM + lane];
            atomicAdd(&dwrep[((size_t)(v & (DREP - 1)) << 15) + (k << 6) + lane], xv);
        }
    } else {
        // ---------------- enc write: one full 268 MB pass -------------------
        const int eb = bid - DW_BLOCKS;                    // 0..ENC_BLOCKS-1
        const size_t nf4 = 16777215;                       // (67108864-4)/4
        float4* body = reinterpret_cast<float4*>(enc + 2); // 16B-aligned
        const size_t stride = (size_t)ENC_BLOCKS * 256;

        for (size_t g = (size_t)eb * 256 + t; g < nf4; g += stride) {
            const size_t e0 = 4 * g + 2;                   // element index of .x
            const int r0 = (int)(e0 >> 9);
            const int r1 = (int)((e0 + 3) >> 9);
            const int i0 = idx[r0];
            const int i1 = (r1 != r0) ? idx[r1] : i0;
            float4 v;
            v.x = ((int)(e0 & 511) == i0) ? 1.f : 0.f;
            v.y = ((int)((e0 + 1) & 511) == (((e0 + 1) >> 9) == (size_t)r0 ? i0 : i1)) ? 1.f : 0.f;
            v.z = ((int)((e0 + 2) & 511) == (((e0 + 2) >> 9) == (size_t)r0 ? i0 : i1)) ? 1.f : 0.f;
            v.w = ((int)((e0 + 3) & 511) == (((e0 + 3) >> 9) == (size_t)r0 ? i0 : i1)) ? 1.f : 0.f;
            body[g] = v;
        }

        if (eb == 0 && t == 0) {
            const int k0 = idx[0];
            enc[0] = (k0 == 0) ? 1.f : 0.f;
            enc[1] = (k0 == 1) ? 1.f : 0.f;
            const int kL = idx[N_VEC - 1];
            enc[67108862] = (kL == 510) ? 1.f : 0.f;
            enc[67108863] = (kL == 511) ? 1.f : 0.f;
        }
    }
}

// ---------------------------------------------------------------------------
// emaA: counts replica-reduce + EMA cluster size + Laplace + perplexity.
// ---------------------------------------------------------------------------
__global__ __launch_bounds__(512) void emaA_kernel(
    const float* __restrict__ counts_rep,
    const float* __restrict__ ema_cs,
    float* __restrict__ csbuf,
    float* __restrict__ perp_out)
{
    __shared__ float red[K_CODES];
    const int k = threadIdx.x;
    float cnt = 0.f;
#pragma unroll
    for (int r = 0; r < CREP; ++r) cnt += counts_rep[r * K_CODES + k];
    float cs = ema_cs[k] * 0.99f + 0.01f * cnt;

    red[k] = cs;
    __syncthreads();
    for (int s = K_CODES / 2; s > 0; s >>= 1) {
        if (k < s) red[k] += red[k + s];
        __syncthreads();
    }
    const float n = red[0];
    __syncthreads();

    csbuf[k] = (cs + 1e-5f) / (n + (float)K_CODES * 1e-5f) * n;

    const float p = cnt * (1.0f / (float)N_VEC);
    red[k] = p * logf(p + 1e-10f);
    __syncthreads();
    for (int s = K_CODES / 2; s > 0; s >>= 1) {
        if (k < s) red[k] += red[k + s];
        __syncthreads();
    }
    if (k == 0) perp_out[0] = expf(-red[0]);
}

// ---------------------------------------------------------------------------
// emaB: dw replica-reduce + codebook update. 32768 (k,d) threads.
// ---------------------------------------------------------------------------
__global__ __launch_bounds__(256) void emaB_kernel(
    const float* __restrict__ dwrep,
    const float* __restrict__ ema_w,
    const float* __restrict__ csbuf,
    float* __restrict__ new_emb)
{
    const int t = blockIdx.x * 256 + threadIdx.x;   // 0..32767 = k*64+d
    const int k = t >> 6;
    float dwv = 0.f;
#pragma unroll
    for (int r = 0; r < DREP; ++r) dwv += dwrep[((size_t)r << 15) + t];
    const float v = ema_w[t] * 0.99f + 0.01f * dwv;
    new_emb[t] = v / csbuf[k];
}

// ---------------------------------------------------------------------------
// quantize: gather + straight-through + NHWC->NCHW + commitment loss.
// ---------------------------------------------------------------------------
__global__ __launch_bounds__(256) void quantize_kernel(
    const float* __restrict__ inputs,
    const int* __restrict__ idx,
    const float* __restrict__ new_emb,
    float* __restrict__ out_q,
    float* __restrict__ loss_accum)
{
    __shared__ int sIdx[64];
    __shared__ float tile[DIM][65];
    __shared__ float wsum[4];

    const int bh = blockIdx.x;
    const int b = bh >> 6, h = bh & 63;
    const int t = threadIdx.x;

    if (t < 64) sIdx[t] = idx[bh * 64 + t];
    __syncthreads();

    const float* inRow = inputs + (size_t)bh * 64 * DIM;
    const int d = t & 63;
    const int wg = t >> 6;
    float lsum = 0.f;
#pragma unroll
    for (int p = 0; p < 16; ++p) {
        const int w = wg * 16 + p;
        const float xv = inRow[w * DIM + d];
        const float qv = new_emb[sIdx[w] * DIM + d];
        const float diff = qv - xv;
        tile[d][w] = xv + diff;
        lsum = fmaf(diff, diff, lsum);
    }
    __syncthreads();

    const int w2 = t & 63;
    const int dg = t >> 6;
#pragma unroll
    for (int p = 0; p < 16; ++p) {
        const int d2 = dg * 16 + p;
        out_q[(((size_t)b * DIM + d2) * 64 + h) * 64 + w2] = tile[d2][w2];
    }

    for (int off = 32; off > 0; off >>= 1) lsum += __shfl_down(lsum, off);
    if ((t & 63) == 0) wsum[t >> 6] = lsum;
    __syncthreads();
    if (t == 0) atomicAdd(loss_accum, (wsum[0] + wsum[1]) + (wsum[2] + wsum[3]));
}

__global__ void finalize_kernel(const float* __restrict__ loss_accum,
                                float* __restrict__ out_loss)
{
    out_loss[0] = 0.25f * (loss_accum[0] / 8388608.0f);
}

// ---------------------------------------------------------------------------
extern "C" void kernel_launch(void* const* d_in, const int* in_sizes, int n_in,
                              void* d_out, int out_size, void* d_ws, size_t ws_size,
                              hipStream_t stream)
{
    const float* inputs = (const float*)d_in[0];
    const float* emb_w  = (const float*)d_in[1];
    const float* ema_cs = (const float*)d_in[2];
    const float* ema_w  = (const float*)d_in[3];
    float* out = (float*)d_out;
    float* ws  = (float*)d_ws;

    // ws layout (f32 offsets):
    int*   idxbuf  = (int*)ws;              // [0, 131072)
    float* crep    = ws + 131072;           // [131072, 139264)  16x512
    float* lossac  = ws + 139264;           // [139264]
    float* csbuf   = ws + 139265;           // [139265, 139777)
    float* eebuf   = ws + 139777;           // [139777, 140289)
    float* nemb    = ws + 140289;           // [140289, 173057)
    bfrag* epack   = (bfrag*)(ws + 173060); // 192 KB, 16B-aligned

    // dw replicas (8 MB) in the not-yet-written quantized region of d_out
    // (out+16 -> 64B-aligned); zeroed by argmin, consumed by emaB, then
    // overwritten by quantize.
    float* dwrep = out + 16;

    epack_ee_kernel<<<16, 256, 0, stream>>>(emb_w, epack, eebuf, crep, lossac);

    argmin_mfma_kernel<<<N_VEC / 256, 256, 0, stream>>>(
        inputs, epack, eebuf, idxbuf, crep, dwrep);

    encdw_kernel<<<DW_BLOCKS + ENC_BLOCKS, 256, 0, stream>>>(
        inputs, idxbuf, out + ENC_OFF, dwrep);

    emaA_kernel<<<1, K_CODES, 0, stream>>>(crep, ema_cs, csbuf, out + PERP_OFF);
    emaB_kernel<<<K_CODES * DIM / 256, 256, 0, stream>>>(dwrep, ema_w, csbuf, nemb);

    quantize_kernel<<<32 * 64, 256, 0, stream>>>(
        inputs, idxbuf, nemb, out + Q_OFF, lossac);

    finalize_kernel<<<1, 1, 0, stream>>>(lossac, out);
}